// Round 17
// baseline (798.624 us; speedup 1.0000x reference)
//
#include <hip/hip_runtime.h>
#include <hip/hip_bf16.h>

typedef __attribute__((ext_vector_type(8))) short short8;
typedef __attribute__((ext_vector_type(4))) short short4v;
typedef __attribute__((ext_vector_type(4))) float float4v;

#define MFMA16(a, b, c) __builtin_amdgcn_mfma_f32_16x16x32_bf16(a, b, c, 0, 0, 0)

__device__ __forceinline__ short f2bf(float f) {
    __hip_bfloat16 hb = __float2bfloat16(f);
    return *reinterpret_cast<short*>(&hb);
}
__device__ __forceinline__ float bf2f(short s) {
    __hip_bfloat16 hb = *reinterpret_cast<__hip_bfloat16*>(&s);
    return __bfloat162float(hb);
}

// ---------------------------------------------------------------------------
// Kernel 1: prep (+ fused wt).  z<8: nv/rv f32 -> Vt [b][h][64][1024] bf16.
// z==8: W[512][1024] f32 -> Wt[1024][512] bf16.  grid: (32, 8, 9), block 256.
// (verbatim from R15/R16)
// ---------------------------------------------------------------------------
__global__ __launch_bounds__(256) void prep_kernel(
    const float* __restrict__ nv, const float* __restrict__ rv,
    const float* __restrict__ Wn, const float* __restrict__ Wr,
    __hip_bfloat16* __restrict__ Vtn, __hip_bfloat16* __restrict__ Vtr,
    __hip_bfloat16* __restrict__ Wtn, __hip_bfloat16* __restrict__ Wtr)
{
    __shared__ short lds[64][72];
    const int t = threadIdx.x;

    if (blockIdx.z == 8) {
        const int id = blockIdx.x + 32 * blockIdx.y;   // 0..255
        const int c0 = (id & 15) * 64;
        const int k0 = ((id >> 4) & 7) * 64;
        const int g  = id >> 7;
        const float* W = g ? Wr : Wn;
        __hip_bfloat16* Wt = g ? Wtr : Wtn;
        {
            const int i  = t >> 2;            // k row
            const int j0 = (t & 3) * 16;      // c chunk
            const float* p = W + (size_t)(k0 + i) * 1024 + c0 + j0;
            #pragma unroll
            for (int jj = 0; jj < 16; ++jj)
                lds[j0 + jj][i] = f2bf(p[jj]);  // lds[c][k]
        }
        __syncthreads();
        {
            const int j  = t >> 2;            // c row
            const int i0 = (t & 3) * 16;      // k chunk
            __hip_bfloat16* q = Wt + (size_t)(c0 + j) * 512 + k0 + i0;
            short8 v0 = *reinterpret_cast<const short8*>(&lds[j][i0]);
            short8 v1 = *reinterpret_cast<const short8*>(&lds[j][i0 + 8]);
            *reinterpret_cast<short8*>(q)     = v0;
            *reinterpret_cast<short8*>(q + 8) = v1;
        }
        return;
    }

    const int ntile = blockIdx.x & 15;
    const int src   = blockIdx.x >> 4;
    const int h     = blockIdx.y;
    const int b     = blockIdx.z;
    const float* V  = src ? rv : nv;
    __hip_bfloat16* Vt = src ? Vtr : Vtn;

    const int n0 = ntile * 64;
    {
        const int i  = t >> 2;            // n within tile
        const int j0 = (t & 3) * 16;      // d chunk
        const float* p = V + ((size_t)(b * 1024) + n0 + i) * 512 + h * 64 + j0;
        #pragma unroll
        for (int jj = 0; jj < 16; ++jj)
            lds[j0 + jj][i] = f2bf(p[jj]);
    }
    __syncthreads();
    {
        const int j  = t >> 2;            // d row
        const int i0 = (t & 3) * 16;      // n chunk
        __hip_bfloat16* q = Vt + (((size_t)(b * 8 + h) * 64) + j) * 1024 + n0 + i0;
        short8 v0 = *reinterpret_cast<const short8*>(&lds[j][i0]);
        short8 v1 = *reinterpret_cast<const short8*>(&lds[j][i0 + 8]);
        *reinterpret_cast<short8*>(q)     = v0;
        *reinterpret_cast<short8*>(q + 8) = v1;
    }
}

// ---------------------------------------------------------------------------
// Kernel 2: projection GEMM.  128m x 256c tile, 2 m-frags/wave (verbatim R16).
// grid: (64 mtiles, 4 ctiles, 2 gemms) = 512 blocks, block 256 (4 waves).
// ---------------------------------------------------------------------------
__global__ __launch_bounds__(256, 2) void proj_kernel(
    const float* __restrict__ nv, const float* __restrict__ rv,
    const __hip_bfloat16* __restrict__ Wtn, const __hip_bfloat16* __restrict__ Wtr,
    const float* __restrict__ bn, const float* __restrict__ br,
    __hip_bfloat16* __restrict__ Qn, __hip_bfloat16* __restrict__ Kn,
    __hip_bfloat16* __restrict__ Qr, __hip_bfloat16* __restrict__ Kr)
{
    const int m0 = blockIdx.x * 128;
    const int c0 = blockIdx.y * 256;
    const int g  = blockIdx.z;
    const float* A = g ? rv : nv;            // [8192][512] f32 row-major
    const __hip_bfloat16* Wt = g ? Wtr : Wtn;
    const float* bias = g ? br : bn;
    __hip_bfloat16* Qd = g ? Qr : Qn;
    __hip_bfloat16* Kd = g ? Kr : Kn;

    __shared__ short Bt[2][4][256][8];   // 32KB

    const int t    = threadIdx.x;
    const int lane = t & 63;
    const int w    = t >> 6;
    const int l15  = lane & 15;
    const int lg   = lane >> 4;

    auto stage = [&](int buf, int kk) {
        #pragma unroll
        for (int rep = 0; rep < 4; ++rep) {
            const int u = rep * 256 + t;        // 16B unit 0..1023
            const int s = u >> 8;               // k-slot 0..3
            const int c = u & 255;
            const __hip_bfloat16* src = Wt + (size_t)(c0 + c) * 512 + kk + s * 8;
            __builtin_amdgcn_global_load_lds(
                (const __attribute__((address_space(1))) unsigned int*)src,
                (__attribute__((address_space(3))) unsigned int*)&Bt[buf][s][c][0],
                16, 0, 0);
        }
    };

    float4v acc[2][16] = {};                 // [mi][cs] = 128 VGPR
    const int mrow0 = m0 + w * 32 + l15;

    stage(0, 0);
    __syncthreads();

    for (int kk = 0; kk < 512; kk += 32) {
        const int buf = (kk >> 5) & 1;
        if (kk < 480) stage(buf ^ 1, kk + 32);
        short8 afrag[2];
        #pragma unroll
        for (int mi = 0; mi < 2; ++mi) {
            const float* ap = A + (size_t)(mrow0 + mi * 16) * 512 + kk + lg * 8;
            float4 a0 = *reinterpret_cast<const float4*>(ap);
            float4 a1 = *reinterpret_cast<const float4*>(ap + 4);
            short* af = (short*)&afrag[mi];
            af[0] = f2bf(a0.x); af[1] = f2bf(a0.y); af[2] = f2bf(a0.z); af[3] = f2bf(a0.w);
            af[4] = f2bf(a1.x); af[5] = f2bf(a1.y); af[6] = f2bf(a1.z); af[7] = f2bf(a1.w);
        }
        #pragma unroll
        for (int cs = 0; cs < 16; ++cs) {
            short8 bfrag = *reinterpret_cast<const short8*>(
                &Bt[buf][lg][cs * 16 + l15][0]);
            acc[0][cs] = MFMA16(afrag[0], bfrag, acc[0][cs]);
            acc[1][cs] = MFMA16(afrag[1], bfrag, acc[1][cs]);
        }
        __syncthreads();
    }

    #pragma unroll
    for (int cs = 0; cs < 16; ++cs) {
        const int c  = c0 + cs * 16 + l15;
        const bool isK = (c >= 512);
        const int hh = (c >> 6) & 7;
        const int d  = c & 63;
        __hip_bfloat16* dst = isK ? Kd : Qd;
        const float bv = bias[c];
        #pragma unroll
        for (int mi = 0; mi < 2; ++mi)
            #pragma unroll
            for (int r = 0; r < 4; ++r) {
                const int m = m0 + w * 32 + mi * 16 + lg * 4 + r;
                const int b = m >> 10, n = m & 1023;
                dst[(((size_t)(b * 8 + hh) * 1024 + n) * 64) + d] =
                    __float2bfloat16(acc[mi][cs][r] + bv);
            }
    }
}

// ---------------------------------------------------------------------------
// Kernel 3: attention, softmax over HEADS.  R17: DIR-FUSED 1024-thread block.
// Waves 0-7 handle dir0, waves 8-15 dir1 (dv = w>>3) for the same (b, ntile):
// 16 waves/CU = 4 waves/SIMD (2x TLP vs R15) with per-CU traffic unchanged.
// Each half runs the R13-proven body: single-buffered K_s (stage issued
// after ns0's barrier = WAR-safe, drains at end-of-iter barrier), bf16 X
// exchange, wave-private P_s.  LDS 136KB = K 2x32 + P 2x20 + Xbf16 2x16.
// SINGLE-ARG __launch_bounds__(1024): 16-wave block mathematically caps
// VGPR at 128 (R13's exact footprint); the 2-arg forms (512,4)/(1024,1)
// triggered 64-VGPR spill builds (R7/R9/R12/R14) and are avoided.
// grid: (8 b, 16 nt) -> id%8 = b: each XCD holds one batch's Kn+Kr+Vtn+Vtr
// = 4MB = L2.  Barriers symmetric across halves (identical schedules).
// ---------------------------------------------------------------------------
__global__ __launch_bounds__(1024) void attn_kernel(
    const __hip_bfloat16* __restrict__ Qn, const __hip_bfloat16* __restrict__ Kn,
    const __hip_bfloat16* __restrict__ Qr, const __hip_bfloat16* __restrict__ Kr,
    const __hip_bfloat16* __restrict__ Vtn, const __hip_bfloat16* __restrict__ Vtr,
    float* __restrict__ out)
{
    const int bb = blockIdx.x;        // 0..7
    const int nt = blockIdx.y;        // 0..15

    const int t    = threadIdx.x;
    const int lane = t & 63;
    const int w    = t >> 6;          // 0..15
    const int dv   = w >> 3;          // dir this wave processes
    const int wl   = w & 7;           // wave within half
    const int iw   = wl & 1;          // n-subtile within pair
    const int hg   = wl >> 1;         // head pair 0..3
    const int h0   = hg * 2;
    const int l15  = lane & 15;
    const int lg   = lane >> 4;       // 0..3

    const __hip_bfloat16* Q  = dv ? Qr  : Qn;
    const __hip_bfloat16* K  = dv ? Kn  : Kr;
    const __hip_bfloat16* Vt = dv ? Vtn : Vtr;
    float* O = out + (size_t)dv * (8u * 1024u * 512u);

    __shared__ short K_s[2][8 * 32 * 64];     // 64KB [dv][h][m][d] slot-swizzled
    __shared__ short P_s[2][8][32][40];       // 40KB [dv], wave-private regions
    __shared__ short Xb[2][2][4][2][64][8];   // 32KB bf16 [dv][ns][hg][iw][lane][p]

    const int n0 = nt * 64;
    const float C = 0.125f * 1.44269504f;     // SCALE * log2(e)

    const __hip_bfloat16* Vb[2] = {
        Vt + (size_t)((bb * 8 + h0)     * 64) * 1024,
        Vt + (size_t)((bb * 8 + h0 + 1) * 64) * 1024 };

    // stage this half's 32KB K tile (8 waves x 4 calls x 64 lanes x 16B)
    auto stage = [&](int mt) {
        #pragma unroll
        for (int i = 0; i < 4; ++i) {
            const int u    = (wl * 4 + i) * 64 + lane;  // 16B unit, 0..2047
            const int h    = u >> 8;                    // 256 units per head
            const int mr   = (u >> 3) & 31;             // row within tile
            const int slot = (u & 7) ^ (mr & 7);        // swizzled 16B slot
            const __hip_bfloat16* g =
                K + ((size_t)((bb * 8 + h) * 1024) + mt + mr) * 64 + slot * 8;
            __builtin_amdgcn_global_load_lds(
                (const __attribute__((address_space(1))) unsigned int*)g,
                (__attribute__((address_space(3))) unsigned int*)&K_s[dv][u * 8],
                16, 0, 0);
        }
    };

    // Q fragments (B operand): qf[ns][hh][kc]
    short8 qf[2][2][2];
    #pragma unroll
    for (int ns = 0; ns < 2; ++ns)
        #pragma unroll
        for (int hh = 0; hh < 2; ++hh)
            #pragma unroll
            for (int kc = 0; kc < 2; ++kc)
                qf[ns][hh][kc] = *reinterpret_cast<const short8*>(
                    Q + ((size_t)((bb * 8 + h0 + hh) * 1024) + n0 + ns * 32 + iw * 16 + l15) * 64
                      + kc * 32 + lg * 8);

    float4v oacc[2][2][4] = {};       // [ns][hh][dd]

    stage(0);
    __syncthreads();                  // drain prologue staging (both halves)

    for (int it = 0; it < 32; ++it) {
        const int m0 = it << 5;
        // ---- V frags: issue early (global, consumed at PV) ----
        short8 vf[2][4];              // [hh][dd]
        #pragma unroll
        for (int hh = 0; hh < 2; ++hh)
            #pragma unroll
            for (int dd = 0; dd < 4; ++dd)
                vf[hh][dd] = *reinterpret_cast<const short8*>(
                    Vb[hh] + (size_t)(dd * 16 + l15) * 1024 + m0 + lg * 8);
        // ---- K frags from staged LDS (swizzled slots) ----
        short8 kf[2][2][2];           // [hh][j][kc]
        const short* ks = K_s[dv];
        #pragma unroll
        for (int hh = 0; hh < 2; ++hh)
            #pragma unroll
            for (int j = 0; j < 2; ++j) {
                const int mr = j * 16 + l15;
                #pragma unroll
                for (int kc = 0; kc < 2; ++kc)
                    kf[hh][j][kc] = *reinterpret_cast<const short8*>(
                        ks + (h0 + hh) * 2048 + mr * 64
                           + (((kc * 4 + lg) ^ (mr & 7)) * 8));
            }

        #pragma unroll
        for (int ns = 0; ns < 2; ++ns) {
            // ---- S^T = K Q^T, exp in-register ----
            float4v sacc[2][2] = {};  // [hh][j]
            #pragma unroll
            for (int hh = 0; hh < 2; ++hh)
                #pragma unroll
                for (int j = 0; j < 2; ++j)
                    #pragma unroll
                    for (int kc = 0; kc < 2; ++kc)
                        sacc[hh][j] = MFMA16(kf[hh][j][kc], qf[ns][hh][kc], sacc[hh][j]);
            float e[2][8];
            float ps[8] = {0.f, 0.f, 0.f, 0.f, 0.f, 0.f, 0.f, 0.f};
            #pragma unroll
            for (int hh = 0; hh < 2; ++hh)
                #pragma unroll
                for (int j = 0; j < 2; ++j)
                    #pragma unroll
                    for (int r = 0; r < 4; ++r) {
                        float ev = exp2f(sacc[hh][j][r] * C);
                        e[hh][j * 4 + r] = ev;
                        ps[j * 4 + r] += ev;
                    }
            // ---- exchange head-partial sums (bf16-packed, b128 ops) ----
            {
                short8 pk;
                #pragma unroll
                for (int p = 0; p < 8; ++p) pk[p] = f2bf(ps[p]);
                *reinterpret_cast<short8*>(&Xb[dv][ns][hg][iw][lane][0]) = pk;
            }
            __syncthreads();
            if (ns == 0)   // stage next iter's K into SAME buffer (WAR-safe:
                stage((it < 31) ? m0 + 32 : 0);   // all kf reads done by barrier)
            float inv[8];
            {
                float tot[8];
                #pragma unroll
                for (int p = 0; p < 8; ++p) tot[p] = ps[p];
                #pragma unroll
                for (int g = 1; g < 4; ++g) {
                    short8 x = *reinterpret_cast<const short8*>(
                        &Xb[dv][ns][(hg + g) & 3][iw][lane][0]);
                    #pragma unroll
                    for (int p = 0; p < 8; ++p) tot[p] += bf2f(x[p]);
                }
                #pragma unroll
                for (int p = 0; p < 8; ++p)
                    inv[p] = __builtin_amdgcn_rcpf(tot[p]);
            }
            // ---- P = e * inv -> wave-private P_s (b64 packed) ----
            #pragma unroll
            for (int hh = 0; hh < 2; ++hh)
                #pragma unroll
                for (int j = 0; j < 2; ++j) {
                    short4v pk;
                    #pragma unroll
                    for (int r = 0; r < 4; ++r)
                        pk[r] = f2bf(e[hh][j * 4 + r] * inv[j * 4 + r]);
                    *reinterpret_cast<short4v*>(
                        &P_s[dv][h0 + hh][iw * 16 + l15][j * 16 + lg * 4]) = pk;
                }
            // ---- O += P V (P_s wave-private: in-wave LDS ordering suffices) ----
            #pragma unroll
            for (int hh = 0; hh < 2; ++hh) {
                short8 pf = *reinterpret_cast<const short8*>(
                    &P_s[dv][h0 + hh][iw * 16 + l15][lg * 8]);
                #pragma unroll
                for (int dd = 0; dd < 4; ++dd)
                    oacc[ns][hh][dd] = MFMA16(pf, vf[hh][dd], oacc[ns][hh][dd]);
            }
        }
        __syncthreads();              // fences X slots + drains staging DMA
    }

    // ---- epilogue: O[b][n][h*64+d] f32 (each half writes its own dir) ----
    #pragma unroll
    for (int ns = 0; ns < 2; ++ns)
        #pragma unroll
        for (int hh = 0; hh < 2; ++hh)
            #pragma unroll
            for (int dd = 0; dd < 4; ++dd)
                #pragma unroll
                for (int r = 0; r < 4; ++r) {
                    const int n = n0 + ns * 32 + iw * 16 + lg * 4 + r;
                    const int d = dd * 16 + l15;
                    O[((size_t)(bb * 1024) + n) * 512 + (h0 + hh) * 64 + d] =
                        oacc[ns][hh][dd][r];
                }
}

extern "C" void kernel_launch(void* const* d_in, const int* in_sizes, int n_in,
                              void* d_out, int out_size, void* d_ws, size_t ws_size,
                              hipStream_t stream) {
    const float* nv = (const float*)d_in[0];
    const float* rv = (const float*)d_in[1];
    const float* Wn = (const float*)d_in[2];
    const float* bn = (const float*)d_in[3];
    const float* Wr = (const float*)d_in[4];
    const float* br = (const float*)d_in[5];
    float* out = (float*)d_out;

    __hip_bfloat16* w = (__hip_bfloat16*)d_ws;
    const size_t E = 8ull * 8 * 1024 * 64;    // 4M elems
    __hip_bfloat16* Qn  = w;
    __hip_bfloat16* Kn  = w + E;
    __hip_bfloat16* Qr  = w + 2 * E;
    __hip_bfloat16* Kr  = w + 3 * E;
    __hip_bfloat16* Vtn = w + 4 * E;
    __hip_bfloat16* Vtr = w + 5 * E;
    __hip_bfloat16* Wtn = w + 6 * E;
    __hip_bfloat16* Wtr = w + 6 * E + 512 * 1024;

    prep_kernel<<<dim3(32, 8, 9), 256, 0, stream>>>(nv, rv, Wn, Wr,
                                                    Vtn, Vtr, Wtn, Wtr);
    proj_kernel<<<dim3(64, 4, 2), 256, 0, stream>>>(nv, rv, Wtn, Wtr, bn, br,
                                                    Qn, Kn, Qr, Kr);
    attn_kernel<<<dim3(8, 16), 1024, 0, stream>>>(Qn, Kn, Qr, Kr, Vtn, Vtr, out);
}

// Round 18
// 460.754 us; speedup vs baseline: 1.7333x; 1.7333x over previous
//
#include <hip/hip_runtime.h>
#include <hip/hip_bf16.h>

typedef __attribute__((ext_vector_type(8))) short short8;
typedef __attribute__((ext_vector_type(4))) short short4v;
typedef __attribute__((ext_vector_type(4))) float float4v;

#define MFMA16(a, b, c) __builtin_amdgcn_mfma_f32_16x16x32_bf16(a, b, c, 0, 0, 0)

__device__ __forceinline__ short f2bf(float f) {
    __hip_bfloat16 hb = __float2bfloat16(f);
    return *reinterpret_cast<short*>(&hb);
}

// ---------------------------------------------------------------------------
// Kernel 1: prep (+ fused wt).  z<8: nv/rv f32 -> Vt [b][h][64][1024] bf16.
// z==8: W[512][1024] f32 -> Wt[1024][512] bf16.  grid: (32, 8, 9), block 256.
// (verbatim R15/R16)
// ---------------------------------------------------------------------------
__global__ __launch_bounds__(256) void prep_kernel(
    const float* __restrict__ nv, const float* __restrict__ rv,
    const float* __restrict__ Wn, const float* __restrict__ Wr,
    __hip_bfloat16* __restrict__ Vtn, __hip_bfloat16* __restrict__ Vtr,
    __hip_bfloat16* __restrict__ Wtn, __hip_bfloat16* __restrict__ Wtr)
{
    __shared__ short lds[64][72];
    const int t = threadIdx.x;

    if (blockIdx.z == 8) {
        const int id = blockIdx.x + 32 * blockIdx.y;   // 0..255
        const int c0 = (id & 15) * 64;
        const int k0 = ((id >> 4) & 7) * 64;
        const int g  = id >> 7;
        const float* W = g ? Wr : Wn;
        __hip_bfloat16* Wt = g ? Wtr : Wtn;
        {
            const int i  = t >> 2;            // k row
            const int j0 = (t & 3) * 16;      // c chunk
            const float* p = W + (size_t)(k0 + i) * 1024 + c0 + j0;
            #pragma unroll
            for (int jj = 0; jj < 16; ++jj)
                lds[j0 + jj][i] = f2bf(p[jj]);  // lds[c][k]
        }
        __syncthreads();
        {
            const int j  = t >> 2;            // c row
            const int i0 = (t & 3) * 16;      // k chunk
            __hip_bfloat16* q = Wt + (size_t)(c0 + j) * 512 + k0 + i0;
            short8 v0 = *reinterpret_cast<const short8*>(&lds[j][i0]);
            short8 v1 = *reinterpret_cast<const short8*>(&lds[j][i0 + 8]);
            *reinterpret_cast<short8*>(q)     = v0;
            *reinterpret_cast<short8*>(q + 8) = v1;
        }
        return;
    }

    const int ntile = blockIdx.x & 15;
    const int src   = blockIdx.x >> 4;
    const int h     = blockIdx.y;
    const int b     = blockIdx.z;
    const float* V  = src ? rv : nv;
    __hip_bfloat16* Vt = src ? Vtr : Vtn;

    const int n0 = ntile * 64;
    {
        const int i  = t >> 2;            // n within tile
        const int j0 = (t & 3) * 16;      // d chunk
        const float* p = V + ((size_t)(b * 1024) + n0 + i) * 512 + h * 64 + j0;
        #pragma unroll
        for (int jj = 0; jj < 16; ++jj)
            lds[j0 + jj][i] = f2bf(p[jj]);
    }
    __syncthreads();
    {
        const int j  = t >> 2;            // d row
        const int i0 = (t & 3) * 16;      // n chunk
        __hip_bfloat16* q = Vt + (((size_t)(b * 8 + h) * 64) + j) * 1024 + n0 + i0;
        short8 v0 = *reinterpret_cast<const short8*>(&lds[j][i0]);
        short8 v1 = *reinterpret_cast<const short8*>(&lds[j][i0 + 8]);
        *reinterpret_cast<short8*>(q)     = v0;
        *reinterpret_cast<short8*>(q + 8) = v1;
    }
}

// ---------------------------------------------------------------------------
// Kernel 2: projection GEMM.  128m x 256c tile, 2 m-frags/wave (verbatim R16).
// grid: (64 mtiles, 4 ctiles, 2 gemms) = 512 blocks, block 256 (4 waves).
// ---------------------------------------------------------------------------
__global__ __launch_bounds__(256, 2) void proj_kernel(
    const float* __restrict__ nv, const float* __restrict__ rv,
    const __hip_bfloat16* __restrict__ Wtn, const __hip_bfloat16* __restrict__ Wtr,
    const float* __restrict__ bn, const float* __restrict__ br,
    __hip_bfloat16* __restrict__ Qn, __hip_bfloat16* __restrict__ Kn,
    __hip_bfloat16* __restrict__ Qr, __hip_bfloat16* __restrict__ Kr)
{
    const int m0 = blockIdx.x * 128;
    const int c0 = blockIdx.y * 256;
    const int g  = blockIdx.z;
    const float* A = g ? rv : nv;            // [8192][512] f32 row-major
    const __hip_bfloat16* Wt = g ? Wtr : Wtn;
    const float* bias = g ? br : bn;
    __hip_bfloat16* Qd = g ? Qr : Qn;
    __hip_bfloat16* Kd = g ? Kr : Kn;

    __shared__ short Bt[2][4][256][8];   // 32KB

    const int t    = threadIdx.x;
    const int lane = t & 63;
    const int w    = t >> 6;
    const int l15  = lane & 15;
    const int lg   = lane >> 4;

    auto stage = [&](int buf, int kk) {
        #pragma unroll
        for (int rep = 0; rep < 4; ++rep) {
            const int u = rep * 256 + t;        // 16B unit 0..1023
            const int s = u >> 8;               // k-slot 0..3
            const int c = u & 255;
            const __hip_bfloat16* src = Wt + (size_t)(c0 + c) * 512 + kk + s * 8;
            __builtin_amdgcn_global_load_lds(
                (const __attribute__((address_space(1))) unsigned int*)src,
                (__attribute__((address_space(3))) unsigned int*)&Bt[buf][s][c][0],
                16, 0, 0);
        }
    };

    float4v acc[2][16] = {};                 // [mi][cs] = 128 VGPR
    const int mrow0 = m0 + w * 32 + l15;

    stage(0, 0);
    __syncthreads();

    for (int kk = 0; kk < 512; kk += 32) {
        const int buf = (kk >> 5) & 1;
        if (kk < 480) stage(buf ^ 1, kk + 32);
        short8 afrag[2];
        #pragma unroll
        for (int mi = 0; mi < 2; ++mi) {
            const float* ap = A + (size_t)(mrow0 + mi * 16) * 512 + kk + lg * 8;
            float4 a0 = *reinterpret_cast<const float4*>(ap);
            float4 a1 = *reinterpret_cast<const float4*>(ap + 4);
            short* af = (short*)&afrag[mi];
            af[0] = f2bf(a0.x); af[1] = f2bf(a0.y); af[2] = f2bf(a0.z); af[3] = f2bf(a0.w);
            af[4] = f2bf(a1.x); af[5] = f2bf(a1.y); af[6] = f2bf(a1.z); af[7] = f2bf(a1.w);
        }
        #pragma unroll
        for (int cs = 0; cs < 16; ++cs) {
            short8 bfrag = *reinterpret_cast<const short8*>(
                &Bt[buf][lg][cs * 16 + l15][0]);
            acc[0][cs] = MFMA16(afrag[0], bfrag, acc[0][cs]);
            acc[1][cs] = MFMA16(afrag[1], bfrag, acc[1][cs]);
        }
        __syncthreads();
    }

    #pragma unroll
    for (int cs = 0; cs < 16; ++cs) {
        const int c  = c0 + cs * 16 + l15;
        const bool isK = (c >= 512);
        const int hh = (c >> 6) & 7;
        const int d  = c & 63;
        __hip_bfloat16* dst = isK ? Kd : Qd;
        const float bv = bias[c];
        #pragma unroll
        for (int mi = 0; mi < 2; ++mi)
            #pragma unroll
            for (int r = 0; r < 4; ++r) {
                const int m = m0 + w * 32 + mi * 16 + lg * 4 + r;
                const int b = m >> 10, n = m & 1023;
                dst[(((size_t)(b * 8 + hh) * 1024 + n) * 64) + d] =
                    __float2bfloat16(acc[mi][cs][r] + bv);
            }
    }
}

// ---------------------------------------------------------------------------
// Kernel 3: attention, softmax over HEADS.  R18 = R16/R10 structure (the ONLY
// non-spilling config: __launch_bounds__(512,2), VGPR 128) with the X
// exchange replaced by ds_add_f32 accumulation (R9-field-verified 3-slot
// rotation): per ns-phase 8 atomicAdd + 8 reads (+8 zeroes on hg==0) instead
// of 8 writes + 24 reads + 24 VALU adds.  Phase q=2*it+ns, par=q%3:
// adds[q] pre-barrier, reads[q] post-barrier, slot (par+2)%3 zeroed in the
// post-region (>=1 barrier from its readers AND from its next adders;
// concurrent ns1-adds hit slot (par+1)%3 - disjoint).  LDS 96KB = K dbuf 64
// + P 20 + Xa 12.  Everything else byte-identical to R16.
// grid: (16 combos = b + 8*dir, 16 ntiles of 64 rows), XCD-local.
// ---------------------------------------------------------------------------
__global__ __launch_bounds__(512, 2) void attn_kernel(
    const __hip_bfloat16* __restrict__ Qn, const __hip_bfloat16* __restrict__ Kn,
    const __hip_bfloat16* __restrict__ Qr, const __hip_bfloat16* __restrict__ Kr,
    const __hip_bfloat16* __restrict__ Vtn, const __hip_bfloat16* __restrict__ Vtr,
    float* __restrict__ out)
{
    const int combo = blockIdx.x;     // 0..15
    const int bb    = combo & 7;
    const int dir   = combo >> 3;
    const int nt    = blockIdx.y;     // 0..15
    const __hip_bfloat16* Q  = dir ? Qr  : Qn;
    const __hip_bfloat16* K  = dir ? Kn  : Kr;
    const __hip_bfloat16* Vt = dir ? Vtn : Vtr;
    float* O = out + (size_t)dir * (8u * 1024u * 512u);

    const int t    = threadIdx.x;
    const int lane = t & 63;
    const int w    = t >> 6;          // 0..7
    const int iw   = w & 1;           // n-subtile within pair
    const int hg   = w >> 1;          // head pair 0..3
    const int h0   = hg * 2;
    const int l15  = lane & 15;
    const int lg   = lane >> 4;       // 0..3

    __shared__ short K_s[2][8 * 32 * 64];   // 64KB: [buf][h][m][d] (slot-swizzled)
    __shared__ short P_s[8][32][40];        // 20KB, wave-private regions
    __shared__ float Xa[3][2][512];         // 12KB 3-slot rotated accumulators

    const int n0 = nt * 64;
    const float C = 0.125f * 1.44269504f;   // SCALE * log2(e)

    const __hip_bfloat16* Vb[2] = {
        Vt + (size_t)((bb * 8 + h0)     * 64) * 1024,
        Vt + (size_t)((bb * 8 + h0 + 1) * 64) * 1024 };

    auto stage = [&](int bufn, int mt) {
        #pragma unroll
        for (int i = 0; i < 4; ++i) {
            const int u    = (w * 4 + i) * 64 + lane;   // 16B unit, 0..2047
            const int h    = u >> 8;                    // 256 units per head
            const int mr   = (u >> 3) & 31;             // row within tile
            const int slot = (u & 7) ^ (mr & 7);        // swizzled 16B slot
            const __hip_bfloat16* g =
                K + ((size_t)((bb * 8 + h) * 1024) + mt + mr) * 64 + slot * 8;
            __builtin_amdgcn_global_load_lds(
                (const __attribute__((address_space(1))) unsigned int*)g,
                (__attribute__((address_space(3))) unsigned int*)&K_s[bufn][u * 8],
                16, 0, 0);
        }
    };

    // Q fragments (B operand): qf[ns][hh][kc]
    short8 qf[2][2][2];
    #pragma unroll
    for (int ns = 0; ns < 2; ++ns)
        #pragma unroll
        for (int hh = 0; hh < 2; ++hh)
            #pragma unroll
            for (int kc = 0; kc < 2; ++kc)
                qf[ns][hh][kc] = *reinterpret_cast<const short8*>(
                    Q + ((size_t)((bb * 8 + h0 + hh) * 1024) + n0 + ns * 32 + iw * 16 + l15) * 64
                      + kc * 32 + lg * 8);

    float4v oacc[2][2][4] = {};       // [ns][hh][dd]

    // prologue: zero all 3 X slots, stage first K tile
    {
        float* xf = &Xa[0][0][0];
        #pragma unroll
        for (int z = 0; z < 6; ++z) xf[t + z * 512] = 0.f;
    }
    stage(0, 0);
    __syncthreads();

    for (int it = 0; it < 32; ++it) {
        const int m0  = it << 5;
        const int buf = it & 1;
        // ---- V frags: issue early (global, consumed at PV) ----
        short8 vf[2][4];              // [hh][dd]
        #pragma unroll
        for (int hh = 0; hh < 2; ++hh)
            #pragma unroll
            for (int dd = 0; dd < 4; ++dd)
                vf[hh][dd] = *reinterpret_cast<const short8*>(
                    Vb[hh] + (size_t)(dd * 16 + l15) * 1024 + m0 + lg * 8);
        // ---- K frags from staged LDS (swizzled slots) ----
        short8 kf[2][2][2];           // [hh][j][kc]
        const short* ks = K_s[buf];
        #pragma unroll
        for (int hh = 0; hh < 2; ++hh)
            #pragma unroll
            for (int j = 0; j < 2; ++j) {
                const int mr = j * 16 + l15;
                #pragma unroll
                for (int kc = 0; kc < 2; ++kc)
                    kf[hh][j][kc] = *reinterpret_cast<const short8*>(
                        ks + (h0 + hh) * 2048 + mr * 64
                           + (((kc * 4 + lg) ^ (mr & 7)) * 8));
            }

        #pragma unroll
        for (int ns = 0; ns < 2; ++ns) {
            const int par = (2 * it + ns) % 3;
            // ---- S^T = K Q^T, exp in-register ----
            float4v sacc[2][2] = {};  // [hh][j]
            #pragma unroll
            for (int hh = 0; hh < 2; ++hh)
                #pragma unroll
                for (int j = 0; j < 2; ++j)
                    #pragma unroll
                    for (int kc = 0; kc < 2; ++kc)
                        sacc[hh][j] = MFMA16(kf[hh][j][kc], qf[ns][hh][kc], sacc[hh][j]);
            float e[2][8];
            float ps[8];
            #pragma unroll
            for (int j = 0; j < 2; ++j)
                #pragma unroll
                for (int r = 0; r < 4; ++r) {
                    float e0 = exp2f(sacc[0][j][r] * C);
                    float e1 = exp2f(sacc[1][j][r] * C);
                    e[0][j * 4 + r] = e0;
                    e[1][j * 4 + r] = e1;
                    ps[j * 4 + r] = e0 + e1;
                }
            // ---- accumulate head-pair partial sums via ds_add_f32 ----
            #pragma unroll
            for (int p = 0; p < 8; ++p)
                atomicAdd(&Xa[par][iw][p * 64 + lane], ps[p]);
            __syncthreads();
            if (ns == 0)   // stage next iter's K; drains at end-of-iter barrier
                stage(buf ^ 1, (it < 31) ? m0 + 32 : 0);
            // ---- totals + rcp; zero the slot 2 phases back ----
            float inv[8];
            #pragma unroll
            for (int p = 0; p < 8; ++p)
                inv[p] = __builtin_amdgcn_rcpf(Xa[par][iw][p * 64 + lane]);
            if (hg == 0) {
                const int zs = (par + 2) % 3;
                #pragma unroll
                for (int p = 0; p < 8; ++p)
                    Xa[zs][iw][p * 64 + lane] = 0.f;
            }
            // ---- P = e * inv -> wave-private P_s (b64 packed) ----
            #pragma unroll
            for (int hh = 0; hh < 2; ++hh)
                #pragma unroll
                for (int j = 0; j < 2; ++j) {
                    short4v pk;
                    #pragma unroll
                    for (int r = 0; r < 4; ++r)
                        pk[r] = f2bf(e[hh][j * 4 + r] * inv[j * 4 + r]);
                    *reinterpret_cast<short4v*>(
                        &P_s[h0 + hh][iw * 16 + l15][j * 16 + lg * 4]) = pk;
                }
            // ---- O += P V (P_s wave-private: in-wave LDS ordering suffices) ----
            #pragma unroll
            for (int hh = 0; hh < 2; ++hh) {
                short8 pf = *reinterpret_cast<const short8*>(
                    &P_s[h0 + hh][iw * 16 + l15][lg * 8]);
                #pragma unroll
                for (int dd = 0; dd < 4; ++dd)
                    oacc[ns][hh][dd] = MFMA16(pf, vf[hh][dd], oacc[ns][hh][dd]);
            }
        }
        __syncthreads();              // fences X slots + drains staging DMA
    }

    // ---- epilogue: O[b][n][h*64+d] f32 ----
    #pragma unroll
    for (int ns = 0; ns < 2; ++ns)
        #pragma unroll
        for (int hh = 0; hh < 2; ++hh)
            #pragma unroll
            for (int dd = 0; dd < 4; ++dd)
                #pragma unroll
                for (int r = 0; r < 4; ++r) {
                    const int n = n0 + ns * 32 + iw * 16 + lg * 4 + r;
                    const int d = dd * 16 + l15;
                    O[((size_t)(bb * 1024) + n) * 512 + (h0 + hh) * 64 + d] =
                        oacc[ns][hh][dd][r];
                }
}

extern "C" void kernel_launch(void* const* d_in, const int* in_sizes, int n_in,
                              void* d_out, int out_size, void* d_ws, size_t ws_size,
                              hipStream_t stream) {
    const float* nv = (const float*)d_in[0];
    const float* rv = (const float*)d_in[1];
    const float* Wn = (const float*)d_in[2];
    const float* bn = (const float*)d_in[3];
    const float* Wr = (const float*)d_in[4];
    const float* br = (const float*)d_in[5];
    float* out = (float*)d_out;

    __hip_bfloat16* w = (__hip_bfloat16*)d_ws;
    const size_t E = 8ull * 8 * 1024 * 64;    // 4M elems
    __hip_bfloat16* Qn  = w;
    __hip_bfloat16* Kn  = w + E;
    __hip_bfloat16* Qr  = w + 2 * E;
    __hip_bfloat16* Kr  = w + 3 * E;
    __hip_bfloat16* Vtn = w + 4 * E;
    __hip_bfloat16* Vtr = w + 5 * E;
    __hip_bfloat16* Wtn = w + 6 * E;
    __hip_bfloat16* Wtr = w + 6 * E + 512 * 1024;

    prep_kernel<<<dim3(32, 8, 9), 256, 0, stream>>>(nv, rv, Wn, Wr,
                                                    Vtn, Vtr, Wtn, Wtr);
    proj_kernel<<<dim3(64, 4, 2), 256, 0, stream>>>(nv, rv, Wtn, Wtr, bn, br,
                                                    Qn, Kn, Qr, Kr);
    attn_kernel<<<dim3(16, 16), 512, 0, stream>>>(Qn, Kn, Qr, Kr, Vtn, Vtr, out);
}

// Round 19
// 165.318 us; speedup vs baseline: 4.8308x; 2.7871x over previous
//
#include <hip/hip_runtime.h>
#include <hip/hip_bf16.h>

typedef __attribute__((ext_vector_type(8))) short short8;
typedef __attribute__((ext_vector_type(4))) short short4v;
typedef __attribute__((ext_vector_type(4))) float float4v;

#define MFMA16(a, b, c) __builtin_amdgcn_mfma_f32_16x16x32_bf16(a, b, c, 0, 0, 0)

__device__ __forceinline__ short f2bf(float f) {
    __hip_bfloat16 hb = __float2bfloat16(f);
    return *reinterpret_cast<short*>(&hb);
}

// ---------------------------------------------------------------------------
// Kernel 1: prep (+ fused wt).  z<8: nv/rv f32 -> Vt [b][h][64][1024] bf16.
// z==8: W[512][1024] f32 -> Wt[1024][512] bf16.  grid: (32, 8, 9), block 256.
// (verbatim R16 — session-best configuration)
// ---------------------------------------------------------------------------
__global__ __launch_bounds__(256) void prep_kernel(
    const float* __restrict__ nv, const float* __restrict__ rv,
    const float* __restrict__ Wn, const float* __restrict__ Wr,
    __hip_bfloat16* __restrict__ Vtn, __hip_bfloat16* __restrict__ Vtr,
    __hip_bfloat16* __restrict__ Wtn, __hip_bfloat16* __restrict__ Wtr)
{
    __shared__ short lds[64][72];
    const int t = threadIdx.x;

    if (blockIdx.z == 8) {
        const int id = blockIdx.x + 32 * blockIdx.y;   // 0..255
        const int c0 = (id & 15) * 64;
        const int k0 = ((id >> 4) & 7) * 64;
        const int g  = id >> 7;
        const float* W = g ? Wr : Wn;
        __hip_bfloat16* Wt = g ? Wtr : Wtn;
        {
            const int i  = t >> 2;            // k row
            const int j0 = (t & 3) * 16;      // c chunk
            const float* p = W + (size_t)(k0 + i) * 1024 + c0 + j0;
            #pragma unroll
            for (int jj = 0; jj < 16; ++jj)
                lds[j0 + jj][i] = f2bf(p[jj]);  // lds[c][k]
        }
        __syncthreads();
        {
            const int j  = t >> 2;            // c row
            const int i0 = (t & 3) * 16;      // k chunk
            __hip_bfloat16* q = Wt + (size_t)(c0 + j) * 512 + k0 + i0;
            short8 v0 = *reinterpret_cast<const short8*>(&lds[j][i0]);
            short8 v1 = *reinterpret_cast<const short8*>(&lds[j][i0 + 8]);
            *reinterpret_cast<short8*>(q)     = v0;
            *reinterpret_cast<short8*>(q + 8) = v1;
        }
        return;
    }

    const int ntile = blockIdx.x & 15;
    const int src   = blockIdx.x >> 4;
    const int h     = blockIdx.y;
    const int b     = blockIdx.z;
    const float* V  = src ? rv : nv;
    __hip_bfloat16* Vt = src ? Vtr : Vtn;

    const int n0 = ntile * 64;
    {
        const int i  = t >> 2;            // n within tile
        const int j0 = (t & 3) * 16;      // d chunk
        const float* p = V + ((size_t)(b * 1024) + n0 + i) * 512 + h * 64 + j0;
        #pragma unroll
        for (int jj = 0; jj < 16; ++jj)
            lds[j0 + jj][i] = f2bf(p[jj]);
    }
    __syncthreads();
    {
        const int j  = t >> 2;            // d row
        const int i0 = (t & 3) * 16;      // n chunk
        __hip_bfloat16* q = Vt + (((size_t)(b * 8 + h) * 64) + j) * 1024 + n0 + i0;
        short8 v0 = *reinterpret_cast<const short8*>(&lds[j][i0]);
        short8 v1 = *reinterpret_cast<const short8*>(&lds[j][i0 + 8]);
        *reinterpret_cast<short8*>(q)     = v0;
        *reinterpret_cast<short8*>(q + 8) = v1;
    }
}

// ---------------------------------------------------------------------------
// Kernel 2: projection GEMM.  128m x 256c tile, 2 m-frags/wave (verbatim R16).
// grid: (64 mtiles, 4 ctiles, 2 gemms) = 512 blocks, block 256 (4 waves).
// ---------------------------------------------------------------------------
__global__ __launch_bounds__(256, 2) void proj_kernel(
    const float* __restrict__ nv, const float* __restrict__ rv,
    const __hip_bfloat16* __restrict__ Wtn, const __hip_bfloat16* __restrict__ Wtr,
    const float* __restrict__ bn, const float* __restrict__ br,
    __hip_bfloat16* __restrict__ Qn, __hip_bfloat16* __restrict__ Kn,
    __hip_bfloat16* __restrict__ Qr, __hip_bfloat16* __restrict__ Kr)
{
    const int m0 = blockIdx.x * 128;
    const int c0 = blockIdx.y * 256;
    const int g  = blockIdx.z;
    const float* A = g ? rv : nv;            // [8192][512] f32 row-major
    const __hip_bfloat16* Wt = g ? Wtr : Wtn;
    const float* bias = g ? br : bn;
    __hip_bfloat16* Qd = g ? Qr : Qn;
    __hip_bfloat16* Kd = g ? Kr : Kn;

    __shared__ short Bt[2][4][256][8];   // 32KB

    const int t    = threadIdx.x;
    const int lane = t & 63;
    const int w    = t >> 6;
    const int l15  = lane & 15;
    const int lg   = lane >> 4;

    auto stage = [&](int buf, int kk) {
        #pragma unroll
        for (int rep = 0; rep < 4; ++rep) {
            const int u = rep * 256 + t;        // 16B unit 0..1023
            const int s = u >> 8;               // k-slot 0..3
            const int c = u & 255;
            const __hip_bfloat16* src = Wt + (size_t)(c0 + c) * 512 + kk + s * 8;
            __builtin_amdgcn_global_load_lds(
                (const __attribute__((address_space(1))) unsigned int*)src,
                (__attribute__((address_space(3))) unsigned int*)&Bt[buf][s][c][0],
                16, 0, 0);
        }
    };

    float4v acc[2][16] = {};                 // [mi][cs] = 128 VGPR
    const int mrow0 = m0 + w * 32 + l15;

    stage(0, 0);
    __syncthreads();

    for (int kk = 0; kk < 512; kk += 32) {
        const int buf = (kk >> 5) & 1;
        if (kk < 480) stage(buf ^ 1, kk + 32);
        short8 afrag[2];
        #pragma unroll
        for (int mi = 0; mi < 2; ++mi) {
            const float* ap = A + (size_t)(mrow0 + mi * 16) * 512 + kk + lg * 8;
            float4 a0 = *reinterpret_cast<const float4*>(ap);
            float4 a1 = *reinterpret_cast<const float4*>(ap + 4);
            short* af = (short*)&afrag[mi];
            af[0] = f2bf(a0.x); af[1] = f2bf(a0.y); af[2] = f2bf(a0.z); af[3] = f2bf(a0.w);
            af[4] = f2bf(a1.x); af[5] = f2bf(a1.y); af[6] = f2bf(a1.z); af[7] = f2bf(a1.w);
        }
        #pragma unroll
        for (int cs = 0; cs < 16; ++cs) {
            short8 bfrag = *reinterpret_cast<const short8*>(
                &Bt[buf][lg][cs * 16 + l15][0]);
            acc[0][cs] = MFMA16(afrag[0], bfrag, acc[0][cs]);
            acc[1][cs] = MFMA16(afrag[1], bfrag, acc[1][cs]);
        }
        __syncthreads();
    }

    #pragma unroll
    for (int cs = 0; cs < 16; ++cs) {
        const int c  = c0 + cs * 16 + l15;
        const bool isK = (c >= 512);
        const int hh = (c >> 6) & 7;
        const int d  = c & 63;
        __hip_bfloat16* dst = isK ? Kd : Qd;
        const float bv = bias[c];
        #pragma unroll
        for (int mi = 0; mi < 2; ++mi)
            #pragma unroll
            for (int r = 0; r < 4; ++r) {
                const int m = m0 + w * 32 + mi * 16 + lg * 4 + r;
                const int b = m >> 10, n = m & 1023;
                dst[(((size_t)(b * 8 + hh) * 1024 + n) * 64) + d] =
                    __float2bfloat16(acc[mi][cs][r] + bv);
            }
    }
}

// ---------------------------------------------------------------------------
// Kernel 3: attention, softmax over HEADS.  R10 structure VERBATIM — the
// empirically validated optimum: __launch_bounds__(512,2) (every other bound
// triggers a 64-VGPR spill build: R7/R9/R12/R14/R17), scalar f32 X exchange
// (beats bf16-b128 by ~7us [R13] and LDS-atomic by ~294us [R18]), K dbuf
// DMA staging with slot-XOR swizzle, V register loads, wave-private P_s.
// grid: (16 combos = b + 8*dir, 16 ntiles of 64 rows), XCD-local.
// Measured signature: 117-119us, VGPR 128, LDS 118784, FETCH 24.7MB.
// ---------------------------------------------------------------------------
__global__ __launch_bounds__(512, 2) void attn_kernel(
    const __hip_bfloat16* __restrict__ Qn, const __hip_bfloat16* __restrict__ Kn,
    const __hip_bfloat16* __restrict__ Qr, const __hip_bfloat16* __restrict__ Kr,
    const __hip_bfloat16* __restrict__ Vtn, const __hip_bfloat16* __restrict__ Vtr,
    float* __restrict__ out)
{
    const int combo = blockIdx.x;     // 0..15
    const int bb    = combo & 7;
    const int dir   = combo >> 3;
    const int nt    = blockIdx.y;     // 0..15
    const __hip_bfloat16* Q  = dir ? Qr  : Qn;
    const __hip_bfloat16* K  = dir ? Kn  : Kr;
    const __hip_bfloat16* Vt = dir ? Vtn : Vtr;
    float* O = out + (size_t)dir * (8u * 1024u * 512u);

    const int t    = threadIdx.x;
    const int lane = t & 63;
    const int w    = t >> 6;          // 0..7
    const int iw   = w & 1;           // n-subtile within pair
    const int hg   = w >> 1;          // head pair 0..3
    const int h0   = hg * 2;
    const int l15  = lane & 15;
    const int lg   = lane >> 4;       // 0..3

    __shared__ short K_s[2][8 * 32 * 64];   // 64KB: [buf][h][m][d] (slot-swizzled)
    __shared__ short P_s[8][32][40];        // 20KB, wave-private regions
    __shared__ float X_s[2][4][2][512];     // 32KB [ns][hg][iw][p*64+lane]

    const int n0 = nt * 64;
    const float C = 0.125f * 1.44269504f;   // SCALE * log2(e)

    const __hip_bfloat16* Vb[2] = {
        Vt + (size_t)((bb * 8 + h0)     * 64) * 1024,
        Vt + (size_t)((bb * 8 + h0 + 1) * 64) * 1024 };

    auto stage = [&](int bufn, int mt) {
        #pragma unroll
        for (int i = 0; i < 4; ++i) {
            const int u    = (w * 4 + i) * 64 + lane;   // 16B unit, 0..2047
            const int h    = u >> 8;                    // 256 units per head
            const int mr   = (u >> 3) & 31;             // row within tile
            const int slot = (u & 7) ^ (mr & 7);        // swizzled 16B slot
            const __hip_bfloat16* g =
                K + ((size_t)((bb * 8 + h) * 1024) + mt + mr) * 64 + slot * 8;
            __builtin_amdgcn_global_load_lds(
                (const __attribute__((address_space(1))) unsigned int*)g,
                (__attribute__((address_space(3))) unsigned int*)&K_s[bufn][u * 8],
                16, 0, 0);
        }
    };

    // Q fragments (B operand): qf[ns][hh][kc]
    short8 qf[2][2][2];
    #pragma unroll
    for (int ns = 0; ns < 2; ++ns)
        #pragma unroll
        for (int hh = 0; hh < 2; ++hh)
            #pragma unroll
            for (int kc = 0; kc < 2; ++kc)
                qf[ns][hh][kc] = *reinterpret_cast<const short8*>(
                    Q + ((size_t)((bb * 8 + h0 + hh) * 1024) + n0 + ns * 32 + iw * 16 + l15) * 64
                      + kc * 32 + lg * 8);

    float4v oacc[2][2][4] = {};       // [ns][hh][dd]

    stage(0, 0);
    __syncthreads();                  // drain prologue staging

    for (int it = 0; it < 32; ++it) {
        const int m0  = it << 5;
        const int buf = it & 1;
        // ---- V frags: issue early (global, consumed at PV) ----
        short8 vf[2][4];              // [hh][dd]
        #pragma unroll
        for (int hh = 0; hh < 2; ++hh)
            #pragma unroll
            for (int dd = 0; dd < 4; ++dd)
                vf[hh][dd] = *reinterpret_cast<const short8*>(
                    Vb[hh] + (size_t)(dd * 16 + l15) * 1024 + m0 + lg * 8);
        // ---- K frags from staged LDS (swizzled slots) ----
        short8 kf[2][2][2];           // [hh][j][kc]
        const short* ks = K_s[buf];
        #pragma unroll
        for (int hh = 0; hh < 2; ++hh)
            #pragma unroll
            for (int j = 0; j < 2; ++j) {
                const int mr = j * 16 + l15;
                #pragma unroll
                for (int kc = 0; kc < 2; ++kc)
                    kf[hh][j][kc] = *reinterpret_cast<const short8*>(
                        ks + (h0 + hh) * 2048 + mr * 64
                           + (((kc * 4 + lg) ^ (mr & 7)) * 8));
            }

        #pragma unroll
        for (int ns = 0; ns < 2; ++ns) {
            // ---- S^T = K Q^T, exp in-register ----
            float4v sacc[2][2] = {};  // [hh][j]
            #pragma unroll
            for (int hh = 0; hh < 2; ++hh)
                #pragma unroll
                for (int j = 0; j < 2; ++j)
                    #pragma unroll
                    for (int kc = 0; kc < 2; ++kc)
                        sacc[hh][j] = MFMA16(kf[hh][j][kc], qf[ns][hh][kc], sacc[hh][j]);
            float e[2][8];
            float ps[8] = {0.f, 0.f, 0.f, 0.f, 0.f, 0.f, 0.f, 0.f};
            #pragma unroll
            for (int hh = 0; hh < 2; ++hh)
                #pragma unroll
                for (int j = 0; j < 2; ++j)
                    #pragma unroll
                    for (int r = 0; r < 4; ++r) {
                        float ev = exp2f(sacc[hh][j][r] * C);
                        e[hh][j * 4 + r] = ev;
                        ps[j * 4 + r] += ev;
                    }
            // ---- exchange head-partial sums (scalar, conflict-free) ----
            #pragma unroll
            for (int p = 0; p < 8; ++p)
                X_s[ns][hg][iw][p * 64 + lane] = ps[p];
            __syncthreads();
            if (ns == 0)   // stage next iter's K; drains at end-of-iter barrier
                stage(buf ^ 1, (it < 31) ? m0 + 32 : 0);
            float inv[8];
            #pragma unroll
            for (int p = 0; p < 8; ++p) {
                float tot = ps[p];
                #pragma unroll
                for (int g = 1; g < 4; ++g)
                    tot += X_s[ns][(hg + g) & 3][iw][p * 64 + lane];
                inv[p] = __builtin_amdgcn_rcpf(tot);
            }
            // ---- P = e * inv -> wave-private P_s (b64 packed) ----
            #pragma unroll
            for (int hh = 0; hh < 2; ++hh)
                #pragma unroll
                for (int j = 0; j < 2; ++j) {
                    short4v pk;
                    #pragma unroll
                    for (int r = 0; r < 4; ++r)
                        pk[r] = f2bf(e[hh][j * 4 + r] * inv[j * 4 + r]);
                    *reinterpret_cast<short4v*>(
                        &P_s[h0 + hh][iw * 16 + l15][j * 16 + lg * 4]) = pk;
                }
            // ---- O += P V (P_s wave-private: in-wave LDS ordering suffices) ----
            #pragma unroll
            for (int hh = 0; hh < 2; ++hh) {
                short8 pf = *reinterpret_cast<const short8*>(
                    &P_s[h0 + hh][iw * 16 + l15][lg * 8]);
                #pragma unroll
                for (int dd = 0; dd < 4; ++dd)
                    oacc[ns][hh][dd] = MFMA16(pf, vf[hh][dd], oacc[ns][hh][dd]);
            }
        }
        __syncthreads();              // fences X slots + drains staging DMA
    }

    // ---- epilogue: O[b][n][h*64+d] f32 ----
    #pragma unroll
    for (int ns = 0; ns < 2; ++ns)
        #pragma unroll
        for (int hh = 0; hh < 2; ++hh)
            #pragma unroll
            for (int dd = 0; dd < 4; ++dd)
                #pragma unroll
                for (int r = 0; r < 4; ++r) {
                    const int n = n0 + ns * 32 + iw * 16 + lg * 4 + r;
                    const int d = dd * 16 + l15;
                    O[((size_t)(bb * 1024) + n) * 512 + (h0 + hh) * 64 + d] =
                        oacc[ns][hh][dd][r];
                }
}

extern "C" void kernel_launch(void* const* d_in, const int* in_sizes, int n_in,
                              void* d_out, int out_size, void* d_ws, size_t ws_size,
                              hipStream_t stream) {
    const float* nv = (const float*)d_in[0];
    const float* rv = (const float*)d_in[1];
    const float* Wn = (const float*)d_in[2];
    const float* bn = (const float*)d_in[3];
    const float* Wr = (const float*)d_in[4];
    const float* br = (const float*)d_in[5];
    float* out = (float*)d_out;

    __hip_bfloat16* w = (__hip_bfloat16*)d_ws;
    const size_t E = 8ull * 8 * 1024 * 64;    // 4M elems
    __hip_bfloat16* Qn  = w;
    __hip_bfloat16* Kn  = w + E;
    __hip_bfloat16* Qr  = w + 2 * E;
    __hip_bfloat16* Kr  = w + 3 * E;
    __hip_bfloat16* Vtn = w + 4 * E;
    __hip_bfloat16* Vtr = w + 5 * E;
    __hip_bfloat16* Wtn = w + 6 * E;
    __hip_bfloat16* Wtr = w + 6 * E + 512 * 1024;

    prep_kernel<<<dim3(32, 8, 9), 256, 0, stream>>>(nv, rv, Wn, Wr,
                                                    Vtn, Vtr, Wtn, Wtr);
    proj_kernel<<<dim3(64, 4, 2), 256, 0, stream>>>(nv, rv, Wtn, Wtr, bn, br,
                                                    Qn, Kn, Qr, Kr);
    attn_kernel<<<dim3(16, 16), 512, 0, stream>>>(Qn, Kn, Qr, Kr, Vtn, Vtr, out);
}